// Round 5
// baseline (360.574 us; speedup 1.0000x reference)
//
#include <hip/hip_runtime.h>
#include <hip/hip_bf16.h>

typedef unsigned short u16;
typedef unsigned int u32;
typedef __attribute__((ext_vector_type(8))) short bf16x8;
typedef __attribute__((ext_vector_type(4))) float f32x4;

#define T_DIM 2048
#define B_DIM 32
#define H_DIM 512
#define M_DIM (T_DIM * B_DIM)

__device__ inline unsigned pack2(float a, float b) {
  union { __hip_bfloat162 h2; unsigned u; } c;
  c.h2 = __float22bfloat162_rn(make_float2(a, b));
  return c.u;
}

// Precompute: r[b*512+h] = hidden[b]·W1[h] + b_attn[h]; u[h] = W3[h]·W_cov;
// W2bf = bf16(W2) in FRAGMENT-MAJOR layout: chunk (f= h>>4, ks= k>>5) of 1KB,
// within chunk: lane (quad= (k>>3)&3, c= h&15) * 16B + (k&7)*2B.
// A wave's MFMA B-fragment load == one contiguous 1KB chunk at base+lane*16.
__global__ __launch_bounds__(256) void prep_kernel(
    const float* __restrict__ hidden, const float* __restrict__ W_attn,
    const float* __restrict__ b_attn, const float* __restrict__ W_cov,
    u16* __restrict__ W2bf, float* __restrict__ r, float* __restrict__ u)
{
  const int tid = blockIdx.x * 256 + threadIdx.x;  // 0..65535
  const int pair = tid >> 2;                       // b*512 + h
  const int kq = tid & 3;
  const int b = pair >> 9, h = pair & 511;

  {
    const float* hid = hidden + b * 512 + kq * 128;
    const float* w1 = W_attn + (size_t)h * 1536 + kq * 128;
    float acc = 0.f;
    #pragma unroll 8
    for (int k = 0; k < 128; k += 4) {
      float4 x = *(const float4*)(hid + k);
      float4 w = *(const float4*)(w1 + k);
      acc += x.x * w.x + x.y * w.y + x.z * w.z + x.w * w.w;
    }
    acc += __shfl_xor(acc, 1);
    acc += __shfl_xor(acc, 2);
    if (kq == 0) r[pair] = acc + b_attn[h];
  }

  {
    int j0 = tid * 4;
    int hh = j0 >> 9, kk = j0 & 511;
    float4 w = *(const float4*)(W_attn + (size_t)hh * 1536 + 512 + kk);
    uint2 p;
    p.x = pack2(w.x, w.y);
    p.y = pack2(w.z, w.w);
    int f = hh >> 4, c = hh & 15;
    int ks = kk >> 5, quad = (kk >> 3) & 3, e = kk & 7;   // e in {0,4}
    *(uint2*)(W2bf + (size_t)((f * 16 + ks) * 64 + quad * 16 + c) * 8 + e) = p;
  }

  if (tid < 2048) {
    int h3 = tid >> 2;
    const float* w3 = W_attn + (size_t)h3 * 1536 + 1024 + kq * 128;
    const float* wc = W_cov + kq * 128;
    float su = 0.f;
    #pragma unroll 8
    for (int k = 0; k < 128; k += 4) {
      float4 a = *(const float4*)(w3 + k);
      float4 c = *(const float4*)(wc + k);
      su += a.x * c.x + a.y * c.y + a.z * c.z + a.w * c.w;
    }
    su += __shfl_xor(su, 1);
    su += __shfl_xor(su, 2);
    if (kq == 0) u[h3] = su;
  }
}

// No LDS, no barriers. Grid: p = y*1024 + mtile (y = n-half). Blocks (m,0) and (m,1)
// are 1024 apart => p % 8 equal => same XCD => shared A-tile hits that XCD's L2.
// Each wave: m-tile 64 rows (4 subtiles), n-slab 64 (4 B-frags). A fp32 loaded
// directly global->VGPR (two dwordx4/frag, full-line pairs), cvt in-register,
// A and B register double-buffered one K-step ahead. acc in AGPRs.
__global__ __launch_bounds__(256, 3) void gemm_score(
    const float* __restrict__ enc, const u16* __restrict__ W2bf,
    const float* __restrict__ r, const float* __restrict__ u,
    const float* __restrict__ vv, const float* __restrict__ cov,
    float* __restrict__ part)
{
  const int p = blockIdx.x;
  const int m0 = (p & 1023) * 64;
  const int y = p >> 10;               // n-half
  const int tid = threadIdx.x;
  const int lane = tid & 63;
  const int w = tid >> 6;              // 0..3
  const int slab = y * 4 + w;          // 0..7 -> n-slab [slab*64, +64)
  const int quad = lane >> 4, col = lane & 15;

  f32x4 acc[4][4] = {};
  const u16* bbase = W2bf + (size_t)(slab * 4) * 8192 + lane * 8;
  const float* abase = enc + (size_t)(m0 + col) * 512 + quad * 8;

  float4 araw[8];
  bf16x8 bbuf[2][4];

  // preload ks=0
  #pragma unroll
  for (int i = 0; i < 4; ++i) {
    araw[i * 2]     = *(const float4*)(abase + i * 8192);
    araw[i * 2 + 1] = *(const float4*)(abase + i * 8192 + 4);
  }
  #pragma unroll
  for (int j = 0; j < 4; ++j)
    bbuf[0][j] = *(const bf16x8*)(bbase + j * 8192);

  #pragma unroll
  for (int ks = 0; ks < 16; ++ks) {
    // convert current raw A -> bf16 frags (frees araw for next prefetch)
    bf16x8 af[4];
    #pragma unroll
    for (int i = 0; i < 4; ++i) {
      uint4 pa;
      pa.x = pack2(araw[i * 2].x,     araw[i * 2].y);
      pa.y = pack2(araw[i * 2].z,     araw[i * 2].w);
      pa.z = pack2(araw[i * 2 + 1].x, araw[i * 2 + 1].y);
      pa.w = pack2(araw[i * 2 + 1].z, araw[i * 2 + 1].w);
      af[i] = *(bf16x8*)&pa;
    }
    // prefetch ks+1 (flies under this step's MFMA)
    if (ks < 15) {
      #pragma unroll
      for (int i = 0; i < 4; ++i) {
        araw[i * 2]     = *(const float4*)(abase + i * 8192 + (ks + 1) * 32);
        araw[i * 2 + 1] = *(const float4*)(abase + i * 8192 + (ks + 1) * 32 + 4);
      }
      #pragma unroll
      for (int j = 0; j < 4; ++j)
        bbuf[(ks + 1) & 1][j] = *(const bf16x8*)(bbase + j * 8192 + (ks + 1) * 512);
    }
    #pragma unroll
    for (int i = 0; i < 4; ++i)
      #pragma unroll
      for (int j = 0; j < 4; ++j)
        acc[i][j] = __builtin_amdgcn_mfma_f32_16x16x32_bf16(af[i], bbuf[ks & 1][j], acc[i][j], 0, 0, 0);
  }

  // ---- Epilogue: e = relu(acc + r[b,h] + cov[b,t]*u[h]); partial = e·v over wave's 64 h ----
  float uj[4], vj[4];
  #pragma unroll
  for (int j = 0; j < 4; ++j) {
    int gh = slab * 64 + j * 16 + col;
    uj[j] = u[gh];
    vj[j] = vv[gh];
  }
  #pragma unroll
  for (int pr = 0; pr < 2; ++pr) {
    #pragma unroll
    for (int reg = 0; reg < 4; ++reg) {
      int b = pr * 16 + quad * 4 + reg;         // = m & 31 (m0 % 64 == 0)
      const float* rb = r + b * 512;
      float rbj[4];
      #pragma unroll
      for (int j = 0; j < 4; ++j) rbj[j] = rb[slab * 64 + j * 16 + col];
      #pragma unroll
      for (int isub = 0; isub < 2; ++isub) {
        int i = pr + isub * 2;
        int t = (m0 >> 5) + isub;
        float cv = cov[b * 2048 + t];
        float s = 0.f;
        #pragma unroll
        for (int j = 0; j < 4; ++j) {
          float e = acc[i][j][reg] + rbj[j] + cv * uj[j];
          e = fmaxf(e, 0.f);
          s += e * vj[j];
        }
        s += __shfl_xor(s, 1);
        s += __shfl_xor(s, 2);
        s += __shfl_xor(s, 4);
        s += __shfl_xor(s, 8);
        if (col == 0) part[(size_t)(slab * 32 + b) * 2048 + t] = s;
      }
    }
  }
}

// Softmax over T per batch + coverage update. 32 blocks x 256 threads. part layout [p][b][t].
__global__ __launch_bounds__(256) void softmax_kernel(
    const float* __restrict__ part, const float* __restrict__ cov, float* __restrict__ out)
{
  const int b = blockIdx.x;
  const int tid = threadIdx.x;
  const int lane = tid & 63, wid = tid >> 6;
  __shared__ float red[4];
  float loc[8];
  float lmax = -3.4e38f;
  #pragma unroll
  for (int i = 0; i < 8; ++i) {
    int t = tid + i * 256;
    float s = 0.f;
    #pragma unroll
    for (int p = 0; p < 8; ++p) s += part[(size_t)(p * 32 + b) * 2048 + t];
    loc[i] = s;
    lmax = fmaxf(lmax, s);
  }
  #pragma unroll
  for (int o = 32; o; o >>= 1) lmax = fmaxf(lmax, __shfl_xor(lmax, o));
  if (lane == 0) red[wid] = lmax;
  __syncthreads();
  float bmax = fmaxf(fmaxf(red[0], red[1]), fmaxf(red[2], red[3]));
  __syncthreads();
  float lsum = 0.f;
  #pragma unroll
  for (int i = 0; i < 8; ++i) { loc[i] = __expf(loc[i] - bmax); lsum += loc[i]; }
  #pragma unroll
  for (int o = 32; o; o >>= 1) lsum += __shfl_xor(lsum, o);
  if (lane == 0) red[wid] = lsum;
  __syncthreads();
  float inv = 1.0f / (red[0] + red[1] + red[2] + red[3]);
  #pragma unroll
  for (int i = 0; i < 8; ++i) {
    int t = tid + i * 256;
    float a = loc[i] * inv;
    out[b * 2048 + t] = a;                               // attn_weights [B,1,T]
    out[65536 + b * 2048 + t] = cov[b * 2048 + t] + a;   // coverage_new [B,T]
  }
}

extern "C" void kernel_launch(void* const* d_in, const int* in_sizes, int n_in,
                              void* d_out, int out_size, void* d_ws, size_t ws_size,
                              hipStream_t stream) {
  const float* hidden = (const float*)d_in[0];   // [1,B,H]
  const float* enc    = (const float*)d_in[1];   // [T,B,H]
  const float* cov    = (const float*)d_in[2];   // [B,T]
  const float* W_attn = (const float*)d_in[3];   // [H,3H]
  const float* b_attn = (const float*)d_in[4];   // [H]
  const float* vv     = (const float*)d_in[5];   // [H]
  const float* W_cov  = (const float*)d_in[6];   // [H,1]
  float* out = (float*)d_out;

  u16* W2bf = (u16*)d_ws;                              // 512 KB (fragment-major)
  float* r  = (float*)((char*)d_ws + 512 * 1024);      // 64 KB
  float* u  = r + 32 * 512;                            // 2 KB
  float* part = u + 512;                               // 8 * 65536 * 4 = 2 MB

  hipLaunchKernelGGL(prep_kernel, dim3(256), dim3(256), 0, stream,
                     hidden, W_attn, b_attn, W_cov, W2bf, r, u);
  hipLaunchKernelGGL(gemm_score, dim3(2048), dim3(256), 0, stream,
                     enc, W2bf, r, u, vv, cov, part);
  hipLaunchKernelGGL(softmax_kernel, dim3(32), dim3(256), 0, stream,
                     part, cov, out);
}

// Round 6
// 269.721 us; speedup vs baseline: 1.3368x; 1.3368x over previous
//
#include <hip/hip_runtime.h>
#include <hip/hip_bf16.h>

typedef unsigned short u16;
typedef unsigned int u32;
typedef __attribute__((ext_vector_type(8))) short bf16x8;
typedef __attribute__((ext_vector_type(4))) float f32x4;

#define T_DIM 2048
#define B_DIM 32
#define H_DIM 512
#define M_DIM (T_DIM * B_DIM)

__device__ inline unsigned pack2(float a, float b) {
  union { __hip_bfloat162 h2; unsigned u; } c;
  c.h2 = __float22bfloat162_rn(make_float2(a, b));
  return c.u;
}

// Precompute: r[b*512+h] = hidden[b]·W1[h] + b_attn[h]; u[h] = W3[h]·W_cov;
// W2bf = bf16(W2) in FRAGMENT-MAJOR layout: chunk (f= h>>4, ks= k>>5) of 1KB,
// within chunk: lane (quad= (k>>3)&3, c= h&15) * 16B + (k&7)*2B.
// A wave's MFMA B-fragment load == one contiguous 1KB chunk at base+lane*16.
__global__ __launch_bounds__(256) void prep_kernel(
    const float* __restrict__ hidden, const float* __restrict__ W_attn,
    const float* __restrict__ b_attn, const float* __restrict__ W_cov,
    u16* __restrict__ W2bf, float* __restrict__ r, float* __restrict__ u)
{
  const int tid = blockIdx.x * 256 + threadIdx.x;  // 0..65535
  const int pair = tid >> 2;                       // b*512 + h
  const int kq = tid & 3;
  const int b = pair >> 9, h = pair & 511;

  {
    const float* hid = hidden + b * 512 + kq * 128;
    const float* w1 = W_attn + (size_t)h * 1536 + kq * 128;
    float acc = 0.f;
    #pragma unroll 8
    for (int k = 0; k < 128; k += 4) {
      float4 x = *(const float4*)(hid + k);
      float4 w = *(const float4*)(w1 + k);
      acc += x.x * w.x + x.y * w.y + x.z * w.z + x.w * w.w;
    }
    acc += __shfl_xor(acc, 1);
    acc += __shfl_xor(acc, 2);
    if (kq == 0) r[pair] = acc + b_attn[h];
  }

  {
    int j0 = tid * 4;
    int hh = j0 >> 9, kk = j0 & 511;
    float4 w = *(const float4*)(W_attn + (size_t)hh * 1536 + 512 + kk);
    uint2 p;
    p.x = pack2(w.x, w.y);
    p.y = pack2(w.z, w.w);
    int f = hh >> 4, c = hh & 15;
    int ks = kk >> 5, quad = (kk >> 3) & 3, e = kk & 7;   // e in {0,4}
    *(uint2*)(W2bf + (size_t)((f * 16 + ks) * 64 + quad * 16 + c) * 8 + e) = p;
  }

  if (tid < 2048) {
    int h3 = tid >> 2;
    const float* w3 = W_attn + (size_t)h3 * 1536 + 1024 + kq * 128;
    const float* wc = W_cov + kq * 128;
    float su = 0.f;
    #pragma unroll 8
    for (int k = 0; k < 128; k += 4) {
      float4 a = *(const float4*)(w3 + k);
      float4 c = *(const float4*)(wc + k);
      su += a.x * c.x + a.y * c.y + a.z * c.z + a.w * c.w;
    }
    su += __shfl_xor(su, 1);
    su += __shfl_xor(su, 2);
    if (kq == 0) u[h3] = su;
  }
}

// One block (512 thr, 8 waves) per 64-row m-tile. Staging: BULK-ISSUE all 16
// float4 A-loads per lane into registers (16KB in flight per wave, 256KB/CU ->
// HBM-saturating), then cvt->LDS (bf16, XOR-swizzled), one barrier. K-loop is
// barrier-free: each wave owns a 64-wide n-slab; B frags are coalesced 1KB loads
// from fragment-major W2bf (L2-resident), register double-buffered.
__global__ __launch_bounds__(512, 4) void gemm_score(
    const float* __restrict__ enc, const u16* __restrict__ W2bf,
    const float* __restrict__ r, const float* __restrict__ u,
    const float* __restrict__ vv, const float* __restrict__ cov,
    float* __restrict__ part)
{
  const int m0 = blockIdx.x * 64;
  const int tid = threadIdx.x;
  const int lane = tid & 63;
  const int w = tid >> 6;             // wave id 0..7 -> n-slab [w*64, w*64+64)
  const int quad = lane >> 4, col = lane & 15;

  __shared__ u16 As[64 * 512];        // 64 KB, [row][k] with 16B-group XOR swizzle

  // ---- Phase 1a: bulk-issue 16 float4 loads (wave w covers rows it*8+w; lane = 16B k-group) ----
  float4 buf[16];
  {
    const float* gbase = enc + (size_t)m0 * 512 + lane * 8;
    #pragma unroll
    for (int it = 0; it < 8; ++it) {
      const float* ga = gbase + (size_t)(it * 8 + w) * 512;
      buf[it * 2]     = *(const float4*)ga;
      buf[it * 2 + 1] = *(const float4*)(ga + 4);
    }
  }
  // ---- Phase 1b: convert + swizzled LDS write (one ds_write_b128 per it) ----
  #pragma unroll
  for (int it = 0; it < 8; ++it) {
    int row = it * 8 + w;
    uint4 p;
    p.x = pack2(buf[it * 2].x,     buf[it * 2].y);
    p.y = pack2(buf[it * 2].z,     buf[it * 2].w);
    p.z = pack2(buf[it * 2 + 1].x, buf[it * 2 + 1].y);
    p.w = pack2(buf[it * 2 + 1].z, buf[it * 2 + 1].w);
    *(uint4*)&As[row * 512 + (lane ^ (row & 7)) * 8] = p;
  }
  __syncthreads();

  // ---- Phase 2: K-loop, no barriers. B frags: coalesced 1KB loads, double-buffered. ----
  f32x4 acc[4][4] = {};
  const u16* bbase = W2bf + (size_t)w * 32768 + lane * 8;  // f-base = w*4; chunk=512 u16

  bf16x8 bcur[4], bnxt[4];
  #pragma unroll
  for (int j = 0; j < 4; ++j)
    bcur[j] = *(const bf16x8*)(bbase + j * 8192);

  #pragma unroll
  for (int ks = 0; ks < 16; ++ks) {
    if (ks < 15) {
      #pragma unroll
      for (int j = 0; j < 4; ++j)
        bnxt[j] = *(const bf16x8*)(bbase + j * 8192 + (ks + 1) * 512);
    }
    #pragma unroll
    for (int i = 0; i < 4; ++i) {
      int row = i * 16 + col;
      bf16x8 af = *(const bf16x8*)&As[row * 512 + ((ks * 4 + quad) ^ (col & 7)) * 8];
      #pragma unroll
      for (int j = 0; j < 4; ++j)
        acc[i][j] = __builtin_amdgcn_mfma_f32_16x16x32_bf16(af, bcur[j], acc[i][j], 0, 0, 0);
    }
    #pragma unroll
    for (int j = 0; j < 4; ++j) bcur[j] = bnxt[j];
  }

  // ---- Epilogue: e = relu(acc + r[b,h] + cov[b,t]*u[h]); partial = e·v over wave's 64 h ----
  float uj[4], vj[4];
  #pragma unroll
  for (int j = 0; j < 4; ++j) {
    int gh = w * 64 + j * 16 + col;
    uj[j] = u[gh];
    vj[j] = vv[gh];
  }
  #pragma unroll
  for (int pr = 0; pr < 2; ++pr) {
    #pragma unroll
    for (int reg = 0; reg < 4; ++reg) {
      int b = pr * 16 + quad * 4 + reg;         // = m & 31 (m0 % 64 == 0)
      const float* rb = r + b * 512;
      float rbj[4];
      #pragma unroll
      for (int j = 0; j < 4; ++j) rbj[j] = rb[w * 64 + j * 16 + col];
      #pragma unroll
      for (int isub = 0; isub < 2; ++isub) {
        int i = pr + isub * 2;
        int t = (m0 >> 5) + isub;
        float cv = cov[b * 2048 + t];
        float s = 0.f;
        #pragma unroll
        for (int j = 0; j < 4; ++j) {
          float e = acc[i][j][reg] + rbj[j] + cv * uj[j];
          e = fmaxf(e, 0.f);
          s += e * vj[j];
        }
        s += __shfl_xor(s, 1);
        s += __shfl_xor(s, 2);
        s += __shfl_xor(s, 4);
        s += __shfl_xor(s, 8);
        if (col == 0) part[(size_t)(w * 32 + b) * 2048 + t] = s;
      }
    }
  }
}

// Softmax over T per batch + coverage update. 32 blocks x 256 threads. part layout [p][b][t].
__global__ __launch_bounds__(256) void softmax_kernel(
    const float* __restrict__ part, const float* __restrict__ cov, float* __restrict__ out)
{
  const int b = blockIdx.x;
  const int tid = threadIdx.x;
  const int lane = tid & 63, wid = tid >> 6;
  __shared__ float red[4];
  float loc[8];
  float lmax = -3.4e38f;
  #pragma unroll
  for (int i = 0; i < 8; ++i) {
    int t = tid + i * 256;
    float s = 0.f;
    #pragma unroll
    for (int p = 0; p < 8; ++p) s += part[(size_t)(p * 32 + b) * 2048 + t];
    loc[i] = s;
    lmax = fmaxf(lmax, s);
  }
  #pragma unroll
  for (int o = 32; o; o >>= 1) lmax = fmaxf(lmax, __shfl_xor(lmax, o));
  if (lane == 0) red[wid] = lmax;
  __syncthreads();
  float bmax = fmaxf(fmaxf(red[0], red[1]), fmaxf(red[2], red[3]));
  __syncthreads();
  float lsum = 0.f;
  #pragma unroll
  for (int i = 0; i < 8; ++i) { loc[i] = __expf(loc[i] - bmax); lsum += loc[i]; }
  #pragma unroll
  for (int o = 32; o; o >>= 1) lsum += __shfl_xor(lsum, o);
  if (lane == 0) red[wid] = lsum;
  __syncthreads();
  float inv = 1.0f / (red[0] + red[1] + red[2] + red[3]);
  #pragma unroll
  for (int i = 0; i < 8; ++i) {
    int t = tid + i * 256;
    float a = loc[i] * inv;
    out[b * 2048 + t] = a;                               // attn_weights [B,1,T]
    out[65536 + b * 2048 + t] = cov[b * 2048 + t] + a;   // coverage_new [B,T]
  }
}

extern "C" void kernel_launch(void* const* d_in, const int* in_sizes, int n_in,
                              void* d_out, int out_size, void* d_ws, size_t ws_size,
                              hipStream_t stream) {
  const float* hidden = (const float*)d_in[0];   // [1,B,H]
  const float* enc    = (const float*)d_in[1];   // [T,B,H]
  const float* cov    = (const float*)d_in[2];   // [B,T]
  const float* W_attn = (const float*)d_in[3];   // [H,3H]
  const float* b_attn = (const float*)d_in[4];   // [H]
  const float* vv     = (const float*)d_in[5];   // [H]
  const float* W_cov  = (const float*)d_in[6];   // [H,1]
  float* out = (float*)d_out;

  u16* W2bf = (u16*)d_ws;                              // 512 KB (fragment-major)
  float* r  = (float*)((char*)d_ws + 512 * 1024);      // 64 KB
  float* u  = r + 32 * 512;                            // 2 KB
  float* part = u + 512;                               // 8 * 65536 * 4 = 2 MB

  hipLaunchKernelGGL(prep_kernel, dim3(256), dim3(256), 0, stream,
                     hidden, W_attn, b_attn, W_cov, W2bf, r, u);
  hipLaunchKernelGGL(gemm_score, dim3(1024), dim3(512), 0, stream,
                     enc, W2bf, r, u, vv, cov, part);
  hipLaunchKernelGGL(softmax_kernel, dim3(32), dim3(256), 0, stream,
                     part, cov, out);
}